// Round 5
// baseline (968.550 us; speedup 1.0000x reference)
//
#include <hip/hip_runtime.h>

namespace {

typedef float v2f __attribute__((ext_vector_type(2)));

constexpr int T_SEQ = 2048;
constexpr int B_SZ  = 512;
constexpr int C_IN  = 8;
constexpr int H_SZ  = 20;
constexpr int P_LEN = 16;                 // steps per phase (barrier period)
constexpr int N_PH  = T_SEQ / P_LEN;      // 128 phases
constexpr int RING  = 2 * P_LEN;          // 32-slot rings (2 phases)
constexpr float LOG2E = 1.44269504088896340736f;

__device__ __forceinline__ float rlane(float v, int lane) {
  return __int_as_float(__builtin_amdgcn_readlane(__float_as_int(v), lane));
}

template<int S>
__device__ __forceinline__ float quad_bcast(float v) {
  return __int_as_float(__builtin_amdgcn_update_dpp(
      __float_as_int(v), __float_as_int(v), S * 0x55, 0xF, 0xF, true));
}

__device__ __forceinline__ v2f fma2(v2f a, v2f b, v2f c) {
  return __builtin_elementwise_fma(a, b, c);   // -> v_pk_fma_f32
}
__device__ __forceinline__ v2f splat2(float s) { v2f r; r.x = s; r.y = s; return r; }
__device__ __forceinline__ v2f zero2() { v2f r; r.x = 0.f; r.y = 0.f; return r; }

// Elementwise activation on both gate sets: sigmoid (g!=2) / tanh (g==2).
__device__ __forceinline__ v2f act2(v2f a, float cm, float am, float ad) {
  float ex = __builtin_amdgcn_exp2f(a.x * cm);
  float ey = __builtin_amdgcn_exp2f(a.y * cm);
  float sx = __builtin_amdgcn_rcpf(1.0f + ex);
  float sy = __builtin_amdgcn_rcpf(1.0f + ey);
  v2f r; r.x = __fmaf_rn(sx, am, ad); r.y = __fmaf_rn(sy, am, ad);
  return r;
}

__device__ __forceinline__ float fast_tanh(float a) {
  float e = __builtin_amdgcn_exp2f(a * (-2.0f * LOG2E));
  float s = __builtin_amdgcn_rcpf(1.0f + e);
  return __fmaf_rn(s, 2.0f, -1.0f);
}

// h[k] broadcast from lane-distributed regs (set1 at lanes 4k, k<16;
// set2 value for k=16..19 at lanes 4*(k-16)).  Inline form: rlane result
// feeds pk_fma directly, no intermediate array.
#define H_BCAST(ha, hb, k) (((k) < 16) ? rlane((ha), 4 * (k)) : rlane((hb), 4 * ((k) - 16)))

__global__ __attribute__((amdgpu_flat_work_group_size(128, 128),
                          amdgpu_waves_per_eu(1, 1)))
void lstm2_fused(const float* __restrict__ x,
                 const float* __restrict__ Wih0, const float* __restrict__ Whh0,
                 const float* __restrict__ bih0, const float* __restrict__ bhh0,
                 const float* __restrict__ Wih1, const float* __restrict__ Whh1,
                 const float* __restrict__ bih1, const float* __restrict__ bhh1,
                 float* __restrict__ out)
{
  // h0 handoff ring: L0 (wave0) -> feeder (wave1).
  __shared__ __align__(16) float hbuf[RING][H_SZ];
  // Per-lane v2f y-dot partials: feeder -> L1 (wave0). 16 KB.
  __shared__ __align__(16) v2f   ybuf[RING][64];
  // Per-lane v2f x-dot partials: feeder -> L0 (wave0). 16 KB.
  __shared__ __align__(16) v2f   xsbuf[RING][64];
  // x broadcast staging, feeder-private.
  __shared__ __align__(16) float xbuf[P_LEN * C_IN];

  const int tid = threadIdx.x;
  const int wv  = tid >> 6;          // 0 = recurrence wave (L0+L1), 1 = feeder
  const int l   = tid & 63;
  const int b   = blockIdx.x;
  const int k1  = l >> 2;            // 0..15
  const int g   = l & 3;             // gate slot: 0=i 1=f 2=g 3=o
  const int k2  = 16 + (k1 & 3);     // 16..19 (replicated)
  const int j1  = g * H_SZ + k1;
  const int j2  = g * H_SZ + k2;

  const bool  isg = (g == 2);
  const float cm  = isg ? (-2.0f * LOG2E) : (-LOG2E);
  const float am  = isg ?  2.0f : 1.0f;
  const float ad  = isg ? -1.0f : 0.0f;

  if (wv == 0) {
    // ========== recurrence wave: L0(t) and L1(t-32) chains interleaved ======
    v2f wh[H_SZ], wq[H_SZ];            // Whh0 / Whh1, gate-set packed
#pragma unroll
    for (int k = 0; k < H_SZ; ++k) {
      wh[k].x = Whh0[j1 * H_SZ + k]; wh[k].y = Whh0[j2 * H_SZ + k];
      wq[k].x = Whh1[j1 * H_SZ + k]; wq[k].y = Whh1[j2 * H_SZ + k];
    }
    v2f bias0; bias0.x = bih0[j1] + bhh0[j1]; bias0.y = bih0[j2] + bhh0[j2];
    v2f bias1; bias1.x = bih1[j1] + bhh1[j1]; bias1.y = bih1[j2] + bhh1[j2];

    float h0a = 0.f, c0a = 0.f, h0b = 0.f, c0b = 0.f;   // L0 state
    float h1a = 0.f, c1a = 0.f, h1b = 0.f, c1b = 0.f;   // L1 state
    float* op = out + b * H_SZ;

    auto stepL0 = [&](int n, v2f Xs) {
      v2f A0 = bias0, A1 = Xs;
#pragma unroll
      for (int k = 0; k < H_SZ; k += 2) {
        float u0 = H_BCAST(h0a, h0b, k);
        float u1 = H_BCAST(h0a, h0b, k + 1);
        A0 = fma2(wh[k],     splat2(u0), A0);
        A1 = fma2(wh[k + 1], splat2(u1), A1);
      }
      v2f A = A0 + A1;
      v2f act = act2(A, cm, am, ad);
      float iv = quad_bcast<0>(act.x), fv = quad_bcast<1>(act.x);
      float gv = quad_bcast<2>(act.x), ov = quad_bcast<3>(act.x);
      c0a = __fmaf_rn(fv, c0a, iv * gv);
      h0a = ov * fast_tanh(c0a);
      iv = quad_bcast<0>(act.y); fv = quad_bcast<1>(act.y);
      gv = quad_bcast<2>(act.y); ov = quad_bcast<3>(act.y);
      c0b = __fmaf_rn(fv, c0b, iv * gv);
      h0b = ov * fast_tanh(c0b);

      const int slot = n & (RING - 1);
      if (g == 0) {
        hbuf[slot][k1] = h0a;
        if (k1 < 4) hbuf[slot][16 + k1] = h0b;
      }
    };

    auto stepL1 = [&](v2f Ys) {
      v2f Q0 = bias1, Q1 = Ys;
#pragma unroll
      for (int k = 0; k < H_SZ; k += 2) {
        float u0 = H_BCAST(h1a, h1b, k);
        float u1 = H_BCAST(h1a, h1b, k + 1);
        Q0 = fma2(wq[k],     splat2(u0), Q0);
        Q1 = fma2(wq[k + 1], splat2(u1), Q1);
      }
      v2f A = Q0 + Q1;
      v2f act = act2(A, cm, am, ad);
      float iv = quad_bcast<0>(act.x), fv = quad_bcast<1>(act.x);
      float gv = quad_bcast<2>(act.x), ov = quad_bcast<3>(act.x);
      c1a = __fmaf_rn(fv, c1a, iv * gv);
      h1a = ov * fast_tanh(c1a);
      iv = quad_bcast<0>(act.y); fv = quad_bcast<1>(act.y);
      gv = quad_bcast<2>(act.y); ov = quad_bcast<3>(act.y);
      c1b = __fmaf_rn(fv, c1b, iv * gv);
      h1b = ov * fast_tanh(c1b);

      if (g == 0) {
        op[k1] = h1a;
        if (k1 < 4) op[16 + k1] = h1b;
      }
      op += B_SZ * H_SZ;
    };

    for (int s = 0; s <= N_PH + 2; ++s) {
      const bool doL0 = (s >= 1 && s <= N_PH);   // L0 phase s-1
      const bool doL1 = (s >= 3);                // L1 phase s-3
      if (doL0 && doL1) {
        const int p0 = s - 1, r = s - 3;
        v2f Xc = xsbuf[(p0 * P_LEN) & (RING - 1)][l];
        v2f Yc = ybuf[(r * P_LEN) & (RING - 1)][l];
        for (int j = 0; j < P_LEN; ++j) {
          v2f Xs = Xc, Ys = Yc;
          if (j + 1 < P_LEN) {          // one-step-ahead partial prefetch
            Xc = xsbuf[(p0 * P_LEN + j + 1) & (RING - 1)][l];
            Yc = ybuf[(r * P_LEN + j + 1) & (RING - 1)][l];
          }
          // Two independent chains in one scheduling region.
          stepL0(p0 * P_LEN + j, Xs);
          stepL1(Ys);
        }
      } else if (doL0) {
        const int p0 = s - 1;
        v2f Xc = xsbuf[(p0 * P_LEN) & (RING - 1)][l];
        for (int j = 0; j < P_LEN; ++j) {
          v2f Xs = Xc;
          if (j + 1 < P_LEN)
            Xc = xsbuf[(p0 * P_LEN + j + 1) & (RING - 1)][l];
          stepL0(p0 * P_LEN + j, Xs);
        }
      } else if (doL1) {
        const int r = s - 3;
        v2f Yc = ybuf[(r * P_LEN) & (RING - 1)][l];
        for (int j = 0; j < P_LEN; ++j) {
          v2f Ys = Yc;
          if (j + 1 < P_LEN)
            Yc = ybuf[(r * P_LEN + j + 1) & (RING - 1)][l];
          stepL1(Ys);
        }
      }
      __syncthreads();
    }
  } else {
    // ================= feeder wave (no recurrence chain) =================
    // Xs[phase s] = Wih0 . x   (consumed by L0 next superstep)
    // Ys[phase s-2] = Wih1 . y0 (consumed by L1 next superstep)
    v2f wx1[C_IN / 2], wx2[C_IN / 2];  // Wih0 rows j1/j2, k-packed
    v2f wy1[H_SZ / 2], wy2[H_SZ / 2];  // Wih1 rows j1/j2, k-packed
#pragma unroll
    for (int t = 0; t < C_IN / 2; ++t) {
      wx1[t].x = Wih0[j1 * C_IN + 2 * t]; wx1[t].y = Wih0[j1 * C_IN + 2 * t + 1];
      wx2[t].x = Wih0[j2 * C_IN + 2 * t]; wx2[t].y = Wih0[j2 * C_IN + 2 * t + 1];
    }
#pragma unroll
    for (int t = 0; t < H_SZ / 2; ++t) {
      wy1[t].x = Wih1[j1 * H_SZ + 2 * t]; wy1[t].y = Wih1[j1 * H_SZ + 2 * t + 1];
      wy2[t].x = Wih1[j2 * H_SZ + 2 * t]; wy2[t].y = Wih1[j2 * H_SZ + 2 * t + 1];
    }

    // Per-lane x slice: element e in [0,128) of a phase -> step e>>3, channel e&7.
    const float* xl = x + (size_t)(l >> 3) * (B_SZ * C_IN) + b * C_IN + (l & 7);
    const size_t halfph = (size_t)8 * B_SZ * C_IN;
    const size_t phstr  = (size_t)P_LEN * B_SZ * C_IN;

    float cur0 = xl[0],     cur1 = xl[halfph];            // phase 0
    float nx0  = xl[phstr], nx1  = xl[phstr + halfph];    // phase 1

    for (int s = 0; s <= N_PH + 2; ++s) {
      // ---- x-dot for phase s ----
      if (s <= N_PH - 1) {
        xbuf[l] = cur0; xbuf[64 + l] = cur1;
        asm volatile("s_waitcnt lgkmcnt(0)" ::: "memory");
        float4 xc0 = ((const float4*)&xbuf[0])[0];
        float4 xc1 = ((const float4*)&xbuf[0])[1];
        for (int j = 0; j < P_LEN; ++j) {
          v2f xp[4];
          xp[0].x = xc0.x; xp[0].y = xc0.y; xp[1].x = xc0.z; xp[1].y = xc0.w;
          xp[2].x = xc1.x; xp[2].y = xc1.y; xp[3].x = xc1.z; xp[3].y = xc1.w;
          if (j + 1 < P_LEN) {
            xc0 = ((const float4*)&xbuf[(j + 1) * C_IN])[0];
            xc1 = ((const float4*)&xbuf[(j + 1) * C_IN])[1];
          }
          v2f X1 = zero2(), X2 = zero2();
#pragma unroll
          for (int t = 0; t < C_IN / 2; ++t) {
            X1 = fma2(wx1[t], xp[t], X1);
            X2 = fma2(wx2[t], xp[t], X2);
          }
          v2f Xs; Xs.x = X1.x + X1.y; Xs.y = X2.x + X2.y;
          xsbuf[(s * P_LEN + j) & (RING - 1)][l] = Xs;
        }
        cur0 = nx0; cur1 = nx1;
        if (s + 2 <= N_PH - 1) {
          nx0 = xl[(size_t)(s + 2) * phstr];
          nx1 = xl[(size_t)(s + 2) * phstr + halfph];
        }
      }
      // ---- y-dot for phase s-2 ----
      if (s >= 2 && s <= N_PH + 1) {
        const int q = s - 2;
        for (int j = 0; j < P_LEN; ++j) {
          const int slot = (q * P_LEN + j) & (RING - 1);
          const float4* sp = (const float4*)hbuf[slot];
          float4 y0 = sp[0], y1 = sp[1], y2 = sp[2], y3 = sp[3], y4 = sp[4];
          v2f yp[H_SZ / 2];
          yp[0].x = y0.x; yp[0].y = y0.y; yp[1].x = y0.z; yp[1].y = y0.w;
          yp[2].x = y1.x; yp[2].y = y1.y; yp[3].x = y1.z; yp[3].y = y1.w;
          yp[4].x = y2.x; yp[4].y = y2.y; yp[5].x = y2.z; yp[5].y = y2.w;
          yp[6].x = y3.x; yp[6].y = y3.y; yp[7].x = y3.z; yp[7].y = y3.w;
          yp[8].x = y4.x; yp[8].y = y4.y; yp[9].x = y4.z; yp[9].y = y4.w;

          v2f Y1a = zero2(), Y1b = zero2(), Y2a = zero2(), Y2b = zero2();
#pragma unroll
          for (int t = 0; t < H_SZ / 2; t += 2) {
            Y1a = fma2(wy1[t],     yp[t],     Y1a);
            Y2a = fma2(wy2[t],     yp[t],     Y2a);
            Y1b = fma2(wy1[t + 1], yp[t + 1], Y1b);
            Y2b = fma2(wy2[t + 1], yp[t + 1], Y2b);
          }
          v2f Y1 = Y1a + Y1b, Y2 = Y2a + Y2b;
          v2f Ys; Ys.x = Y1.x + Y1.y; Ys.y = Y2.x + Y2.y;
          ybuf[slot][l] = Ys;
        }
      }
      __syncthreads();
    }
  }
}

} // namespace

extern "C" void kernel_launch(void* const* d_in, const int* in_sizes, int n_in,
                              void* d_out, int out_size, void* d_ws, size_t ws_size,
                              hipStream_t stream) {
  const float* x    = (const float*)d_in[0];
  const float* Wih0 = (const float*)d_in[1];
  const float* Whh0 = (const float*)d_in[2];
  const float* bih0 = (const float*)d_in[3];
  const float* bhh0 = (const float*)d_in[4];
  const float* Wih1 = (const float*)d_in[5];
  const float* Whh1 = (const float*)d_in[6];
  const float* bih1 = (const float*)d_in[7];
  const float* bhh1 = (const float*)d_in[8];
  float* out = (float*)d_out;

  hipLaunchKernelGGL(lstm2_fused, dim3(B_SZ), dim3(128), 0, stream,
                     x, Wih0, Whh0, bih0, bhh0, Wih1, Whh1, bih1, bhh1, out);
}